// Round 22
// baseline (263.760 us; speedup 1.0000x reference)
//
#include <hip/hip_runtime.h>
#include <hip/hip_fp16.h>

#define NN 100000
#define NE 1600000
// IN_FEAT=128, N_HEADS=8, OUT_FEAT=16, H*F=128

static __device__ __forceinline__ unsigned short f32_to_bf16_rne(float x) {
    unsigned int u = __float_as_uint(x);
    u += 0x7fff + ((u >> 16) & 1);   // round-to-nearest-even
    return (unsigned short)(u >> 16);
}
static __device__ __forceinline__ float bf16_to_f32(unsigned int bits16) {
    return __uint_as_float(bits16 << 16);
}

// pack layout per node n (32 B record, 2 nodes per 64 B line), as __half indices:
//   [n*16 + h]      : s_tgt[h] stored as bf16 bits   (16 B)
//   [n*16 + 8 + h]  : denom[h] as f16 accumulator    (16 B)
// -> denom pass touches ONE random tgt line per edge (read s_tgt + atomic denom same line).

// ---------------- Kernel 1: fused proj-GEMM + attention scores (r13/r18-measured 64-row tile) ----------------
__global__ __launch_bounds__(256) void gemm_score_kernel(const float* __restrict__ x,
                                                         const float* __restrict__ W,
                                                         const float* __restrict__ a_src,
                                                         const float* __restrict__ a_tgt,
                                                         unsigned short* __restrict__ projT,
                                                         unsigned short* __restrict__ s_src_b,
                                                         __half* __restrict__ pack) {
    __shared__ float sXT[32][68];   // k-major, padded
    __shared__ float sW[32][128];
    const int t = threadIdx.x;
    const int n0 = blockIdx.x * 64;
    const int c0 = (t & 31) * 4;    // head h=c0>>4, first feat f0=c0&15
    const int r0 = t >> 5;          // row group 0..7
    float acc[8][4];
#pragma unroll
    for (int i = 0; i < 8; i++)
#pragma unroll
        for (int j = 0; j < 4; j++) acc[i][j] = 0.f;

    for (int kt = 0; kt < 128; kt += 32) {
#pragma unroll
        for (int p = 0; p < 2; p++) {
            int idx = t + p * 256;
            int r = idx >> 3;
            int kk = idx & 7;
            float4 v = make_float4(0.f, 0.f, 0.f, 0.f);
            int n = n0 + r;
            if (n < NN) v = *reinterpret_cast<const float4*>(&x[(size_t)n * 128 + kt + kk * 4]);
            sXT[kk * 4 + 0][r] = v.x;
            sXT[kk * 4 + 1][r] = v.y;
            sXT[kk * 4 + 2][r] = v.z;
            sXT[kk * 4 + 3][r] = v.w;
        }
#pragma unroll
        for (int p = 0; p < 4; p++) {
            int idx = t + p * 256;
            int kr = idx >> 5;
            int c4 = idx & 31;
            float4 v = *reinterpret_cast<const float4*>(&W[(size_t)(kt + kr) * 128 + c4 * 4]);
            *reinterpret_cast<float4*>(&sW[kr][c4 * 4]) = v;
        }
        __syncthreads();
#pragma unroll
        for (int k = 0; k < 32; k++) {
            float4 xa = *reinterpret_cast<const float4*>(&sXT[k][r0 * 8]);
            float4 xb = *reinterpret_cast<const float4*>(&sXT[k][r0 * 8 + 4]);
            float4 wv = *reinterpret_cast<const float4*>(&sW[k][c0]);
            float xs[8] = {xa.x, xa.y, xa.z, xa.w, xb.x, xb.y, xb.z, xb.w};
#pragma unroll
            for (int i = 0; i < 8; i++) {
                acc[i][0] += xs[i] * wv.x;
                acc[i][1] += xs[i] * wv.y;
                acc[i][2] += xs[i] * wv.z;
                acc[i][3] += xs[i] * wv.w;
            }
        }
        __syncthreads();
    }
    const int h  = c0 >> 4;
    const int f0 = c0 & 15;
    const float aS0 = a_src[c0], aS1 = a_src[c0 + 1], aS2 = a_src[c0 + 2], aS3 = a_src[c0 + 3];
    const float aT0 = a_tgt[c0], aT1 = a_tgt[c0 + 1], aT2 = a_tgt[c0 + 2], aT3 = a_tgt[c0 + 3];
#pragma unroll
    for (int i = 0; i < 8; i++) {
        int n = n0 + r0 * 8 + i;
        if (n < NN) {
            unsigned short* pT = &projT[(size_t)n * 128];
#pragma unroll
            for (int j = 0; j < 4; j++) pT[(f0 + j) * 8 + h] = f32_to_bf16_rne(acc[i][j]);
            float ss = acc[i][0] * aS0 + acc[i][1] * aS1 + acc[i][2] * aS2 + acc[i][3] * aS3;
            float st = acc[i][0] * aT0 + acc[i][1] * aT1 + acc[i][2] * aT2 + acc[i][3] * aT3;
            ss += __shfl_xor(ss, 1);
            ss += __shfl_xor(ss, 2);
            st += __shfl_xor(st, 1);
            st += __shfl_xor(st, 2);
            if ((t & 3) == 0) {
                s_src_b[(size_t)n * 8 + h] = f32_to_bf16_rne(ss);
                reinterpret_cast<unsigned short*>(pack)[(size_t)n * 16 + h] = f32_to_bf16_rne(st);
            }
        }
    }
}

// ---------------- Kernel 2: denom via packed-f16 HW atomics, single tgt line ----------------
// 4 lanes per edge; lane q handles heads (2q, 2q+1). The s_tgt read and the denom
// atomic hit the SAME 64B line (pack record) -> 2 random lines/edge (was 3).
__global__ __launch_bounds__(256) void denom_kernel(const int* __restrict__ src,
                                                    const int* __restrict__ tgt,
                                                    const unsigned short* __restrict__ s_src_b,
                                                    __half* __restrict__ pack,
                                                    unsigned short* __restrict__ exb) {
    int gid = blockIdx.x * blockDim.x + threadIdx.x;
    int e = gid >> 2;
    if (e >= NE) return;
    int h0 = (gid & 3) * 2;
    int s = src[e], t = tgt[e];
    unsigned int ssp = *reinterpret_cast<const unsigned int*>(&s_src_b[(size_t)s * 8 + h0]);
    unsigned int stp = *reinterpret_cast<const unsigned int*>(
        &reinterpret_cast<const unsigned short*>(pack)[(size_t)t * 16 + h0]);
    float v0 = bf16_to_f32(ssp & 0xffffu) + bf16_to_f32(stp & 0xffffu);
    float v1 = bf16_to_f32(ssp >> 16) + bf16_to_f32(stp >> 16);
    v0 = v0 >= 0.f ? v0 : 0.2f * v0;
    v1 = v1 >= 0.f ? v1 : 0.2f * v1;
    float ex0 = expf(v0), ex1 = expf(v1);
    unsigned int pk = (unsigned int)f32_to_bf16_rne(ex0) | ((unsigned int)f32_to_bf16_rne(ex1) << 16);
    *reinterpret_cast<unsigned int*>(&exb[(size_t)e * 8 + h0]) = pk;
    unsafeAtomicAdd(reinterpret_cast<__half2*>(&pack[(size_t)t * 16 + 8 + h0]),
                    __floats2half2_rn(ex0, ex1));
}

// ---------------- Kernel 3: aggregate via packed-f16 HW atomics (frozen from r18) ----------------
__global__ __launch_bounds__(256) void aggregate_kernel(const int* __restrict__ src,
                                                        const int* __restrict__ tgt,
                                                        const __half* __restrict__ pack,
                                                        const unsigned short* __restrict__ exb,
                                                        const unsigned short* __restrict__ projT,
                                                        __half* __restrict__ out_h) {
    int gid = blockIdx.x * blockDim.x + threadIdx.x;
    int e = gid >> 3;
    if (e >= NE) return;
    int j = gid & 7;       // head j; features 2j, 2j+1
    int s = src[e], t = tgt[e];
    float ex = bf16_to_f32(exb[(size_t)e * 8 + j]);
    float dj = __half2float(pack[(size_t)t * 16 + 8 + j]);
    float alpha = ex / (dj + 1e-16f);
    uint4 va = *reinterpret_cast<const uint4*>(&projT[(size_t)s * 128 + (2 * j) * 8]);
    uint4 vb = *reinterpret_cast<const uint4*>(&projT[(size_t)s * 128 + (2 * j + 1) * 8]);
    float m0 = 0.f, m1 = 0.f;
#pragma unroll
    for (int k = 0; k < 8; k++) {
        float ak = __shfl(alpha, k, 8);
        unsigned int wa = (k & 1) ? ((&va.x)[k >> 1] >> 16) : ((&va.x)[k >> 1] & 0xffffu);
        unsigned int wb = (k & 1) ? ((&vb.x)[k >> 1] >> 16) : ((&vb.x)[k >> 1] & 0xffffu);
        m0 += ak * bf16_to_f32(wa);
        m1 += ak * bf16_to_f32(wb);
    }
    unsafeAtomicAdd(reinterpret_cast<__half2*>(&out_h[(size_t)t * 16 + 2 * j]),
                    __floats2half2_rn(m0 * 0.125f, m1 * 0.125f));
}

// ---------------- Kernel 4: bias + softmax over 16 features ----------------
__global__ __launch_bounds__(256) void softmax_kernel(const __half* __restrict__ out_h,
                                                      const float* __restrict__ bias,
                                                      float* __restrict__ out) {
    int gid = blockIdx.x * blockDim.x + threadIdx.x;
    int n = gid >> 4;
    int lane = gid & 15;
    if (n >= NN) return;
    float v = __half2float(out_h[(size_t)n * 16 + lane]) + bias[lane];
    float mx = v;
#pragma unroll
    for (int m = 1; m < 16; m <<= 1) mx = fmaxf(mx, __shfl_xor(mx, m, 64));
    float ex = expf(v - mx);
    float sum = ex;
#pragma unroll
    for (int m = 1; m < 16; m <<= 1) sum += __shfl_xor(sum, m, 64);
    out[(size_t)n * 16 + lane] = ex / sum;
}

extern "C" void kernel_launch(void* const* d_in, const int* in_sizes, int n_in,
                              void* d_out, int out_size, void* d_ws, size_t ws_size,
                              hipStream_t stream) {
    const float* x     = (const float*)d_in[0];
    const int*   ei    = (const int*)d_in[1];
    const float* W     = (const float*)d_in[2];
    const float* a_src = (const float*)d_in[3];
    const float* a_tgt = (const float*)d_in[4];
    const float* bias  = (const float*)d_in[5];
    float* out = (float*)d_out;

    const int* src = ei;            // edge_index[0]
    const int* tgt = ei + NE;       // edge_index[1]

    char* ws = (char*)d_ws;
    size_t off = 0;
    auto alloc = [&](size_t bytes) {
        char* p = ws + off;
        off += (bytes + 255) & ~(size_t)255;
        return p;
    };
    unsigned short* projT   = (unsigned short*)alloc((size_t)NN * 128 * 2); // 25.6 MB bf16, f-major
    unsigned short* exb     = (unsigned short*)alloc((size_t)NE * 8 * 2);   // 25.6 MB bf16 ex[e][h]
    unsigned short* s_src_b = (unsigned short*)alloc((size_t)NN * 8 * 2);   // 1.6 MB
    __half*         pack    = (__half*)alloc((size_t)NN * 16 * 2);          // 3.2 MB s_tgt+denom records
    __half*         out_h   = (__half*)alloc((size_t)NN * 16 * 2);          // 3.2 MB f16

    // zero accumulators every call (pack: denom halves zeroed; s_tgt halves overwritten by gemm)
    hipMemsetAsync(pack, 0, (size_t)NN * 16 * 2, stream);
    hipMemsetAsync(out_h, 0, (size_t)NN * 16 * 2, stream);

    gemm_score_kernel<<<(NN + 63) / 64, 256, 0, stream>>>(x, W, a_src, a_tgt, projT, s_src_b, pack);
    denom_kernel<<<((size_t)NE * 4 + 255) / 256, 256, 0, stream>>>(src, tgt, s_src_b, pack, exb);
    aggregate_kernel<<<((size_t)NE * 8 + 255) / 256, 256, 0, stream>>>(src, tgt, pack, exb,
                                                                       projT, out_h);
    softmax_kernel<<<(NN * 16 + 255) / 256, 256, 0, stream>>>(out_h, bias, out);
}

// Round 23
// 246.147 us; speedup vs baseline: 1.0716x; 1.0716x over previous
//
#include <hip/hip_runtime.h>
#include <hip/hip_fp16.h>

#define NN 100000
#define NE 1600000
// IN_FEAT=128, N_HEADS=8, OUT_FEAT=16, H*F=128

static __device__ __forceinline__ unsigned short f32_to_bf16_rne(float x) {
    unsigned int u = __float_as_uint(x);
    u += 0x7fff + ((u >> 16) & 1);   // round-to-nearest-even
    return (unsigned short)(u >> 16);
}
static __device__ __forceinline__ float bf16_to_f32(unsigned int bits16) {
    return __uint_as_float(bits16 << 16);
}

// ---- fp8 e4m3fn (OCP) software convert: bias 7, max normal 448, e=15&m=7 is NaN (never emitted)
static __device__ __forceinline__ unsigned int f32_to_e4m3(float x) {
    unsigned int u = __float_as_uint(x);
    unsigned int s = (u >> 31) << 7;
    float ax = fabsf(x);
    if (ax >= 448.f) return s | 0x7E;            // clamp to +-448 (e=15, m=6)
    if (ax < 0.0009765625f) return s;            // < 2^-10 -> +-0
    if (ax < 0.015625f) {                        // subnormal: m * 2^-9
        int m = (int)rintf(ax * 512.f);
        return s | (unsigned int)m;              // m==8 naturally encodes min normal (e=1,m=0)
    }
    unsigned int au = __float_as_uint(ax);
    unsigned int mant = au & 0x7FFFFFu;
    unsigned int exp  = au >> 23;                // 121..135
    unsigned int keep = mant >> 20;
    unsigned int rest = mant & 0xFFFFFu;
    keep += (rest > 0x80000u) || (rest == 0x80000u && (keep & 1));
    if (keep == 8) { keep = 0; exp++; }
    return s | ((exp - 120) << 3) | keep;
}
static __device__ __forceinline__ float e4m3_to_f32(unsigned int b) {
    unsigned int e = (b >> 3) & 0xF, m = b & 7;
    float v = (e == 0) ? (float)m * 0.001953125f                    // m * 2^-9
                       : __uint_as_float(((e + 120) << 23) | (m << 20));
    return (b & 0x80) ? -v : v;
}

// ---------------- Kernel 1: fused proj-GEMM + attention scores (r13/r18-measured 64-row tile) ----------------
// projT8: fp8 e4m3, feature-major: projT8[n*128 + f*8 + h] (128 B/row -> 2 cache lines).
__global__ __launch_bounds__(256) void gemm_score_kernel(const float* __restrict__ x,
                                                         const float* __restrict__ W,
                                                         const float* __restrict__ a_src,
                                                         const float* __restrict__ a_tgt,
                                                         unsigned char* __restrict__ projT8,
                                                         unsigned short* __restrict__ s_src_b,
                                                         unsigned short* __restrict__ s_tgt_b) {
    __shared__ float sXT[32][68];   // k-major, padded
    __shared__ float sW[32][128];
    const int t = threadIdx.x;
    const int n0 = blockIdx.x * 64;
    const int c0 = (t & 31) * 4;    // head h=c0>>4, first feat f0=c0&15
    const int r0 = t >> 5;          // row group 0..7
    float acc[8][4];
#pragma unroll
    for (int i = 0; i < 8; i++)
#pragma unroll
        for (int j = 0; j < 4; j++) acc[i][j] = 0.f;

    for (int kt = 0; kt < 128; kt += 32) {
#pragma unroll
        for (int p = 0; p < 2; p++) {
            int idx = t + p * 256;
            int r = idx >> 3;
            int kk = idx & 7;
            float4 v = make_float4(0.f, 0.f, 0.f, 0.f);
            int n = n0 + r;
            if (n < NN) v = *reinterpret_cast<const float4*>(&x[(size_t)n * 128 + kt + kk * 4]);
            sXT[kk * 4 + 0][r] = v.x;
            sXT[kk * 4 + 1][r] = v.y;
            sXT[kk * 4 + 2][r] = v.z;
            sXT[kk * 4 + 3][r] = v.w;
        }
#pragma unroll
        for (int p = 0; p < 4; p++) {
            int idx = t + p * 256;
            int kr = idx >> 5;
            int c4 = idx & 31;
            float4 v = *reinterpret_cast<const float4*>(&W[(size_t)(kt + kr) * 128 + c4 * 4]);
            *reinterpret_cast<float4*>(&sW[kr][c4 * 4]) = v;
        }
        __syncthreads();
#pragma unroll
        for (int k = 0; k < 32; k++) {
            float4 xa = *reinterpret_cast<const float4*>(&sXT[k][r0 * 8]);
            float4 xb = *reinterpret_cast<const float4*>(&sXT[k][r0 * 8 + 4]);
            float4 wv = *reinterpret_cast<const float4*>(&sW[k][c0]);
            float xs[8] = {xa.x, xa.y, xa.z, xa.w, xb.x, xb.y, xb.z, xb.w};
#pragma unroll
            for (int i = 0; i < 8; i++) {
                acc[i][0] += xs[i] * wv.x;
                acc[i][1] += xs[i] * wv.y;
                acc[i][2] += xs[i] * wv.z;
                acc[i][3] += xs[i] * wv.w;
            }
        }
        __syncthreads();
    }
    const int h  = c0 >> 4;
    const int f0 = c0 & 15;
    const float aS0 = a_src[c0], aS1 = a_src[c0 + 1], aS2 = a_src[c0 + 2], aS3 = a_src[c0 + 3];
    const float aT0 = a_tgt[c0], aT1 = a_tgt[c0 + 1], aT2 = a_tgt[c0 + 2], aT3 = a_tgt[c0 + 3];
#pragma unroll
    for (int i = 0; i < 8; i++) {
        int n = n0 + r0 * 8 + i;
        if (n < NN) {
            unsigned char* pT = &projT8[(size_t)n * 128];
#pragma unroll
            for (int j = 0; j < 4; j++) pT[(f0 + j) * 8 + h] = (unsigned char)f32_to_e4m3(acc[i][j]);
            float ss = acc[i][0] * aS0 + acc[i][1] * aS1 + acc[i][2] * aS2 + acc[i][3] * aS3;
            float st = acc[i][0] * aT0 + acc[i][1] * aT1 + acc[i][2] * aT2 + acc[i][3] * aT3;
            ss += __shfl_xor(ss, 1);
            ss += __shfl_xor(ss, 2);
            st += __shfl_xor(st, 1);
            st += __shfl_xor(st, 2);
            if ((t & 3) == 0) {
                s_src_b[(size_t)n * 8 + h] = f32_to_bf16_rne(ss);
                s_tgt_b[(size_t)n * 8 + h] = f32_to_bf16_rne(st);
            }
        }
    }
}

// ---------------- Kernel 2: denom via packed-f16 HW atomics (r18-measured, separate arrays) ----------------
__global__ __launch_bounds__(256) void denom_kernel(const int* __restrict__ src,
                                                    const int* __restrict__ tgt,
                                                    const unsigned short* __restrict__ s_src_b,
                                                    const unsigned short* __restrict__ s_tgt_b,
                                                    __half* __restrict__ denom_h,
                                                    unsigned short* __restrict__ exb) {
    int gid = blockIdx.x * blockDim.x + threadIdx.x;
    int e = gid >> 2;
    if (e >= NE) return;
    int h0 = (gid & 3) * 2;
    int s = src[e], t = tgt[e];
    unsigned int ssp = *reinterpret_cast<const unsigned int*>(&s_src_b[(size_t)s * 8 + h0]);
    unsigned int stp = *reinterpret_cast<const unsigned int*>(&s_tgt_b[(size_t)t * 8 + h0]);
    float v0 = bf16_to_f32(ssp & 0xffffu) + bf16_to_f32(stp & 0xffffu);
    float v1 = bf16_to_f32(ssp >> 16) + bf16_to_f32(stp >> 16);
    v0 = v0 >= 0.f ? v0 : 0.2f * v0;
    v1 = v1 >= 0.f ? v1 : 0.2f * v1;
    float ex0 = expf(v0), ex1 = expf(v1);
    unsigned int pk = (unsigned int)f32_to_bf16_rne(ex0) | ((unsigned int)f32_to_bf16_rne(ex1) << 16);
    *reinterpret_cast<unsigned int*>(&exb[(size_t)e * 8 + h0]) = pk;
    unsafeAtomicAdd(reinterpret_cast<__half2*>(&denom_h[(size_t)t * 8 + h0]),
                    __floats2half2_rn(ex0, ex1));
}

// ---------------- Kernel 3: aggregate — fp8 projT gather (2 lines/edge), packed-f16 atomics ----------------
__global__ __launch_bounds__(256) void aggregate_kernel(const int* __restrict__ src,
                                                        const int* __restrict__ tgt,
                                                        const __half* __restrict__ denom_h,
                                                        const unsigned short* __restrict__ exb,
                                                        const unsigned char* __restrict__ projT8,
                                                        __half* __restrict__ out_h) {
    int gid = blockIdx.x * blockDim.x + threadIdx.x;
    int e = gid >> 3;
    if (e >= NE) return;
    int j = gid & 7;       // head j; features 2j, 2j+1
    int s = src[e], t = tgt[e];
    float ex = bf16_to_f32(exb[(size_t)e * 8 + j]);
    float dj = __half2float(denom_h[(size_t)t * 8 + j]);
    float alpha = ex / (dj + 1e-16f);
    // one 16B load: bytes 0..7 = feature 2j (heads 0..7), bytes 8..15 = feature 2j+1
    uint4 v = *reinterpret_cast<const uint4*>(&projT8[(size_t)s * 128 + j * 16]);
    float m0 = 0.f, m1 = 0.f;
#pragma unroll
    for (int k = 0; k < 8; k++) {
        float ak = __shfl(alpha, k, 8);
        unsigned int ba = ((k < 4 ? v.x : v.y) >> (8 * (k & 3))) & 0xFFu;
        unsigned int bb = ((k < 4 ? v.z : v.w) >> (8 * (k & 3))) & 0xFFu;
        m0 += ak * e4m3_to_f32(ba);
        m1 += ak * e4m3_to_f32(bb);
    }
    unsafeAtomicAdd(reinterpret_cast<__half2*>(&out_h[(size_t)t * 16 + 2 * j]),
                    __floats2half2_rn(m0 * 0.125f, m1 * 0.125f));
}

// ---------------- Kernel 4: bias + softmax over 16 features ----------------
__global__ __launch_bounds__(256) void softmax_kernel(const __half* __restrict__ out_h,
                                                      const float* __restrict__ bias,
                                                      float* __restrict__ out) {
    int gid = blockIdx.x * blockDim.x + threadIdx.x;
    int n = gid >> 4;
    int lane = gid & 15;
    if (n >= NN) return;
    float v = __half2float(out_h[(size_t)n * 16 + lane]) + bias[lane];
    float mx = v;
#pragma unroll
    for (int m = 1; m < 16; m <<= 1) mx = fmaxf(mx, __shfl_xor(mx, m, 64));
    float ex = expf(v - mx);
    float sum = ex;
#pragma unroll
    for (int m = 1; m < 16; m <<= 1) sum += __shfl_xor(sum, m, 64);
    out[(size_t)n * 16 + lane] = ex / sum;
}

extern "C" void kernel_launch(void* const* d_in, const int* in_sizes, int n_in,
                              void* d_out, int out_size, void* d_ws, size_t ws_size,
                              hipStream_t stream) {
    const float* x     = (const float*)d_in[0];
    const int*   ei    = (const int*)d_in[1];
    const float* W     = (const float*)d_in[2];
    const float* a_src = (const float*)d_in[3];
    const float* a_tgt = (const float*)d_in[4];
    const float* bias  = (const float*)d_in[5];
    float* out = (float*)d_out;

    const int* src = ei;            // edge_index[0]
    const int* tgt = ei + NE;       // edge_index[1]

    char* ws = (char*)d_ws;
    size_t off = 0;
    auto alloc = [&](size_t bytes) {
        char* p = ws + off;
        off += (bytes + 255) & ~(size_t)255;
        return p;
    };
    unsigned char*  projT8  = (unsigned char*)alloc((size_t)NN * 128);      // 12.8 MB fp8, f-major
    unsigned short* exb     = (unsigned short*)alloc((size_t)NE * 8 * 2);   // 25.6 MB bf16 ex[e][h]
    unsigned short* s_src_b = (unsigned short*)alloc((size_t)NN * 8 * 2);   // 1.6 MB
    unsigned short* s_tgt_b = (unsigned short*)alloc((size_t)NN * 8 * 2);   // 1.6 MB
    __half*         denom_h = (__half*)alloc((size_t)NN * 8 * 2);           // 1.6 MB f16
    __half*         out_h   = (__half*)alloc((size_t)NN * 16 * 2);          // 3.2 MB f16

    // zero accumulators every call (f16 +0.0 is all-zero bits)
    hipMemsetAsync(denom_h, 0, (size_t)NN * 8 * 2, stream);
    hipMemsetAsync(out_h, 0, (size_t)NN * 16 * 2, stream);

    gemm_score_kernel<<<(NN + 63) / 64, 256, 0, stream>>>(x, W, a_src, a_tgt, projT8,
                                                          s_src_b, s_tgt_b);
    denom_kernel<<<((size_t)NE * 4 + 255) / 256, 256, 0, stream>>>(src, tgt, s_src_b, s_tgt_b,
                                                                   denom_h, exb);
    aggregate_kernel<<<((size_t)NE * 8 + 255) / 256, 256, 0, stream>>>(src, tgt, denom_h, exb,
                                                                       projT8, out_h);
    softmax_kernel<<<(NN * 16 + 255) / 256, 256, 0, stream>>>(out_h, bias, out);
}

// Round 24
// 238.373 us; speedup vs baseline: 1.1065x; 1.0326x over previous
//
#include <hip/hip_runtime.h>
#include <hip/hip_fp16.h>

#define NN 100000
#define NE 1600000
// IN_FEAT=128, N_HEADS=8, OUT_FEAT=16, H*F=128

typedef __attribute__((ext_vector_type(2))) float f32x2;

static __device__ __forceinline__ unsigned short f32_to_bf16_rne(float x) {
    unsigned int u = __float_as_uint(x);
    u += 0x7fff + ((u >> 16) & 1);   // round-to-nearest-even
    return (unsigned short)(u >> 16);
}
static __device__ __forceinline__ float bf16_to_f32(unsigned int bits16) {
    return __uint_as_float(bits16 << 16);
}

// ---------------- Kernel 1: fused proj-GEMM + attention scores (r13/r18-measured 64-row tile) ----------------
// projT8: fp8 e4m3 (OCP, HW cvt), feature-major: projT8[n*128 + f*8 + h] (128 B/row -> 2 lines).
__global__ __launch_bounds__(256) void gemm_score_kernel(const float* __restrict__ x,
                                                         const float* __restrict__ W,
                                                         const float* __restrict__ a_src,
                                                         const float* __restrict__ a_tgt,
                                                         unsigned char* __restrict__ projT8,
                                                         unsigned short* __restrict__ s_src_b,
                                                         unsigned short* __restrict__ s_tgt_b) {
    __shared__ float sXT[32][68];   // k-major, padded
    __shared__ float sW[32][128];
    const int t = threadIdx.x;
    const int n0 = blockIdx.x * 64;
    const int c0 = (t & 31) * 4;    // head h=c0>>4, first feat f0=c0&15
    const int r0 = t >> 5;          // row group 0..7
    float acc[8][4];
#pragma unroll
    for (int i = 0; i < 8; i++)
#pragma unroll
        for (int j = 0; j < 4; j++) acc[i][j] = 0.f;

    for (int kt = 0; kt < 128; kt += 32) {
#pragma unroll
        for (int p = 0; p < 2; p++) {
            int idx = t + p * 256;
            int r = idx >> 3;
            int kk = idx & 7;
            float4 v = make_float4(0.f, 0.f, 0.f, 0.f);
            int n = n0 + r;
            if (n < NN) v = *reinterpret_cast<const float4*>(&x[(size_t)n * 128 + kt + kk * 4]);
            sXT[kk * 4 + 0][r] = v.x;
            sXT[kk * 4 + 1][r] = v.y;
            sXT[kk * 4 + 2][r] = v.z;
            sXT[kk * 4 + 3][r] = v.w;
        }
#pragma unroll
        for (int p = 0; p < 4; p++) {
            int idx = t + p * 256;
            int kr = idx >> 5;
            int c4 = idx & 31;
            float4 v = *reinterpret_cast<const float4*>(&W[(size_t)(kt + kr) * 128 + c4 * 4]);
            *reinterpret_cast<float4*>(&sW[kr][c4 * 4]) = v;
        }
        __syncthreads();
#pragma unroll
        for (int k = 0; k < 32; k++) {
            float4 xa = *reinterpret_cast<const float4*>(&sXT[k][r0 * 8]);
            float4 xb = *reinterpret_cast<const float4*>(&sXT[k][r0 * 8 + 4]);
            float4 wv = *reinterpret_cast<const float4*>(&sW[k][c0]);
            float xs[8] = {xa.x, xa.y, xa.z, xa.w, xb.x, xb.y, xb.z, xb.w};
#pragma unroll
            for (int i = 0; i < 8; i++) {
                acc[i][0] += xs[i] * wv.x;
                acc[i][1] += xs[i] * wv.y;
                acc[i][2] += xs[i] * wv.z;
                acc[i][3] += xs[i] * wv.w;
            }
        }
        __syncthreads();
    }
    const int h  = c0 >> 4;
    const int f0 = c0 & 15;
    const float aS0 = a_src[c0], aS1 = a_src[c0 + 1], aS2 = a_src[c0 + 2], aS3 = a_src[c0 + 3];
    const float aT0 = a_tgt[c0], aT1 = a_tgt[c0 + 1], aT2 = a_tgt[c0 + 2], aT3 = a_tgt[c0 + 3];
#pragma unroll
    for (int i = 0; i < 8; i++) {
        int n = n0 + r0 * 8 + i;
        if (n < NN) {
            unsigned char* pT = &projT8[(size_t)n * 128];
            // HW fp8 encode: 2 values per instruction (low 16 bits of result)
            unsigned int e01 = __builtin_amdgcn_cvt_pk_fp8_f32(acc[i][0], acc[i][1], 0, false);
            unsigned int e23 = __builtin_amdgcn_cvt_pk_fp8_f32(acc[i][2], acc[i][3], 0, false);
            pT[(f0 + 0) * 8 + h] = (unsigned char)(e01 & 0xFF);
            pT[(f0 + 1) * 8 + h] = (unsigned char)((e01 >> 8) & 0xFF);
            pT[(f0 + 2) * 8 + h] = (unsigned char)(e23 & 0xFF);
            pT[(f0 + 3) * 8 + h] = (unsigned char)((e23 >> 8) & 0xFF);
            float ss = acc[i][0] * aS0 + acc[i][1] * aS1 + acc[i][2] * aS2 + acc[i][3] * aS3;
            float st = acc[i][0] * aT0 + acc[i][1] * aT1 + acc[i][2] * aT2 + acc[i][3] * aT3;
            ss += __shfl_xor(ss, 1);
            ss += __shfl_xor(ss, 2);
            st += __shfl_xor(st, 1);
            st += __shfl_xor(st, 2);
            if ((t & 3) == 0) {
                s_src_b[(size_t)n * 8 + h] = f32_to_bf16_rne(ss);
                s_tgt_b[(size_t)n * 8 + h] = f32_to_bf16_rne(st);
            }
        }
    }
}

// ---------------- Kernel 2: denom via packed-f16 HW atomics (r18-measured, separate arrays) ----------------
__global__ __launch_bounds__(256) void denom_kernel(const int* __restrict__ src,
                                                    const int* __restrict__ tgt,
                                                    const unsigned short* __restrict__ s_src_b,
                                                    const unsigned short* __restrict__ s_tgt_b,
                                                    __half* __restrict__ denom_h,
                                                    unsigned short* __restrict__ exb) {
    int gid = blockIdx.x * blockDim.x + threadIdx.x;
    int e = gid >> 2;
    if (e >= NE) return;
    int h0 = (gid & 3) * 2;
    int s = src[e], t = tgt[e];
    unsigned int ssp = *reinterpret_cast<const unsigned int*>(&s_src_b[(size_t)s * 8 + h0]);
    unsigned int stp = *reinterpret_cast<const unsigned int*>(&s_tgt_b[(size_t)t * 8 + h0]);
    float v0 = bf16_to_f32(ssp & 0xffffu) + bf16_to_f32(stp & 0xffffu);
    float v1 = bf16_to_f32(ssp >> 16) + bf16_to_f32(stp >> 16);
    v0 = v0 >= 0.f ? v0 : 0.2f * v0;
    v1 = v1 >= 0.f ? v1 : 0.2f * v1;
    float ex0 = expf(v0), ex1 = expf(v1);
    unsigned int pk = (unsigned int)f32_to_bf16_rne(ex0) | ((unsigned int)f32_to_bf16_rne(ex1) << 16);
    *reinterpret_cast<unsigned int*>(&exb[(size_t)e * 8 + h0]) = pk;
    unsafeAtomicAdd(reinterpret_cast<__half2*>(&denom_h[(size_t)t * 8 + h0]),
                    __floats2half2_rn(ex0, ex1));
}

// ---------------- Kernel 3: aggregate — fp8 gather (2 lines/edge) + HW fp8 decode ----------------
__global__ __launch_bounds__(256) void aggregate_kernel(const int* __restrict__ src,
                                                        const int* __restrict__ tgt,
                                                        const __half* __restrict__ denom_h,
                                                        const unsigned short* __restrict__ exb,
                                                        const unsigned char* __restrict__ projT8,
                                                        __half* __restrict__ out_h) {
    int gid = blockIdx.x * blockDim.x + threadIdx.x;
    int e = gid >> 3;
    if (e >= NE) return;
    int j = gid & 7;       // head j; features 2j, 2j+1
    int s = src[e], t = tgt[e];
    float ex = bf16_to_f32(exb[(size_t)e * 8 + j]);
    float dj = __half2float(denom_h[(size_t)t * 8 + j]);
    float alpha = ex / (dj + 1e-16f);
    // one 16B load: v.x,v.y = feature 2j heads 0..7; v.z,v.w = feature 2j+1 heads 0..7
    uint4 v = *reinterpret_cast<const uint4*>(&projT8[(size_t)s * 128 + j * 16]);
    // HW fp8 decode: 2 floats per instruction
    f32x2 a01 = __builtin_amdgcn_cvt_pk_f32_fp8(v.x, false);
    f32x2 a23 = __builtin_amdgcn_cvt_pk_f32_fp8(v.x, true);
    f32x2 a45 = __builtin_amdgcn_cvt_pk_f32_fp8(v.y, false);
    f32x2 a67 = __builtin_amdgcn_cvt_pk_f32_fp8(v.y, true);
    f32x2 b01 = __builtin_amdgcn_cvt_pk_f32_fp8(v.z, false);
    f32x2 b23 = __builtin_amdgcn_cvt_pk_f32_fp8(v.z, true);
    f32x2 b45 = __builtin_amdgcn_cvt_pk_f32_fp8(v.w, false);
    f32x2 b67 = __builtin_amdgcn_cvt_pk_f32_fp8(v.w, true);
    float pa[8] = {a01.x, a01.y, a23.x, a23.y, a45.x, a45.y, a67.x, a67.y};
    float pb[8] = {b01.x, b01.y, b23.x, b23.y, b45.x, b45.y, b67.x, b67.y};
    float m0 = 0.f, m1 = 0.f;
#pragma unroll
    for (int k = 0; k < 8; k++) {
        float ak = __shfl(alpha, k, 8);
        m0 += ak * pa[k];
        m1 += ak * pb[k];
    }
    unsafeAtomicAdd(reinterpret_cast<__half2*>(&out_h[(size_t)t * 16 + 2 * j]),
                    __floats2half2_rn(m0 * 0.125f, m1 * 0.125f));
}

// ---------------- Kernel 4: bias + softmax over 16 features ----------------
__global__ __launch_bounds__(256) void softmax_kernel(const __half* __restrict__ out_h,
                                                      const float* __restrict__ bias,
                                                      float* __restrict__ out) {
    int gid = blockIdx.x * blockDim.x + threadIdx.x;
    int n = gid >> 4;
    int lane = gid & 15;
    if (n >= NN) return;
    float v = __half2float(out_h[(size_t)n * 16 + lane]) + bias[lane];
    float mx = v;
#pragma unroll
    for (int m = 1; m < 16; m <<= 1) mx = fmaxf(mx, __shfl_xor(mx, m, 64));
    float ex = expf(v - mx);
    float sum = ex;
#pragma unroll
    for (int m = 1; m < 16; m <<= 1) sum += __shfl_xor(sum, m, 64);
    out[(size_t)n * 16 + lane] = ex / sum;
}

extern "C" void kernel_launch(void* const* d_in, const int* in_sizes, int n_in,
                              void* d_out, int out_size, void* d_ws, size_t ws_size,
                              hipStream_t stream) {
    const float* x     = (const float*)d_in[0];
    const int*   ei    = (const int*)d_in[1];
    const float* W     = (const float*)d_in[2];
    const float* a_src = (const float*)d_in[3];
    const float* a_tgt = (const float*)d_in[4];
    const float* bias  = (const float*)d_in[5];
    float* out = (float*)d_out;

    const int* src = ei;            // edge_index[0]
    const int* tgt = ei + NE;       // edge_index[1]

    char* ws = (char*)d_ws;
    size_t off = 0;
    auto alloc = [&](size_t bytes) {
        char* p = ws + off;
        off += (bytes + 255) & ~(size_t)255;
        return p;
    };
    unsigned char*  projT8  = (unsigned char*)alloc((size_t)NN * 128);      // 12.8 MB fp8, f-major
    unsigned short* exb     = (unsigned short*)alloc((size_t)NE * 8 * 2);   // 25.6 MB bf16 ex[e][h]
    unsigned short* s_src_b = (unsigned short*)alloc((size_t)NN * 8 * 2);   // 1.6 MB
    unsigned short* s_tgt_b = (unsigned short*)alloc((size_t)NN * 8 * 2);   // 1.6 MB
    __half*         denom_h = (__half*)alloc((size_t)NN * 8 * 2);           // 1.6 MB f16
    __half*         out_h   = (__half*)alloc((size_t)NN * 16 * 2);          // 3.2 MB f16

    // zero accumulators every call (f16 +0.0 is all-zero bits)
    hipMemsetAsync(denom_h, 0, (size_t)NN * 8 * 2, stream);
    hipMemsetAsync(out_h, 0, (size_t)NN * 16 * 2, stream);

    gemm_score_kernel<<<(NN + 63) / 64, 256, 0, stream>>>(x, W, a_src, a_tgt, projT8,
                                                          s_src_b, s_tgt_b);
    denom_kernel<<<((size_t)NE * 4 + 255) / 256, 256, 0, stream>>>(src, tgt, s_src_b, s_tgt_b,
                                                                   denom_h, exb);
    aggregate_kernel<<<((size_t)NE * 8 + 255) / 256, 256, 0, stream>>>(src, tgt, denom_h, exb,
                                                                       projT8, out_h);
    softmax_kernel<<<(NN * 16 + 255) / 256, 256, 0, stream>>>(out_h, bias, out);
}